// Round 5
// baseline (303.565 us; speedup 1.0000x reference)
//
#include <hip/hip_runtime.h>
#include <cstdint>

#define B_DIM 8
#define C_DIM 512
#define L_DIM 2048
#define NGROUPS 32
#define CPG 16
#define EPSV 1e-6f

typedef unsigned short u16;
typedef unsigned int u32;
typedef __attribute__((ext_vector_type(4))) float f32x4;
typedef __attribute__((ext_vector_type(8))) short bf16x8;
typedef const __attribute__((address_space(1))) char gchar;
typedef __attribute__((address_space(3))) char lchar;

__device__ __forceinline__ u16 f2bf(float f) {
  u32 u = __float_as_uint(f);
  u = (u + 0x7fffu + ((u >> 16) & 1u)) >> 16;
  return (u16)u;
}
__device__ __forceinline__ float bf2f(u16 h) {
  return __uint_as_float(((u32)h) << 16);
}

// -------- fused prep: 4x weight fp32->bf16 + bias concat (1 dispatch) --------
__global__ __launch_bounds__(256) void prep_k(
    const float* __restrict__ Wq, const float* __restrict__ Wk,
    const float* __restrict__ Wv, const float* __restrict__ Wp,
    const float* __restrict__ bq, const float* __restrict__ bk,
    u16* __restrict__ wqkb, u16* __restrict__ wvb, u16* __restrict__ wpb,
    float* __restrict__ bqk) {
  const int g = blockIdx.x;
  if (g < 1024) {
    const int w = g >> 8;
    const float* src = w == 0 ? Wq : w == 1 ? Wk : w == 2 ? Wv : Wp;
    u16* dst = w == 0 ? wqkb : w == 1 ? wqkb + C_DIM * C_DIM : w == 2 ? wvb : wpb;
    int i = (g & 255) * 256 + threadIdx.x;  // over CC/4 float4 chunks
    float4 v = ((const float4*)src)[i];
    int2 o;
    o.x = (int)((u32)f2bf(v.x) | ((u32)f2bf(v.y) << 16));
    o.y = (int)((u32)f2bf(v.z) | ((u32)f2bf(v.w) << 16));
    ((int2*)dst)[i] = o;
  } else {
#pragma unroll
    for (int q = 0; q < 4; ++q) {
      int idx = q * 256 + threadIdx.x;
      bqk[idx] = idx < C_DIM ? bq[idx] : bk[idx - C_DIM];
    }
  }
}

// ---------------- GroupNorm stats: one block per (b,g) ----------------
__global__ __launch_bounds__(256) void gn_stats_k(const float* __restrict__ x,
                                                  float* __restrict__ meanp,
                                                  float* __restrict__ rstdp) {
  const int bg = blockIdx.x;
  const float4* xv = (const float4*)(x + (size_t)bg * CPG * L_DIM);
  const int tid = threadIdx.x;
  float s = 0.f, ss = 0.f;
  for (int i = tid; i < CPG * L_DIM / 4; i += 256) {
    float4 v = xv[i];
    s += v.x + v.y + v.z + v.w;
    ss += v.x * v.x + v.y * v.y + v.z * v.z + v.w * v.w;
  }
#pragma unroll
  for (int o = 32; o > 0; o >>= 1) {
    s += __shfl_down(s, o);
    ss += __shfl_down(ss, o);
  }
  __shared__ float r1[4], r2[4];
  if ((tid & 63) == 0) { r1[tid >> 6] = s; r2[tid >> 6] = ss; }
  __syncthreads();
  if (tid == 0) {
    float S = r1[0] + r1[1] + r1[2] + r1[3];
    float SS = r2[0] + r2[1] + r2[2] + r2[3];
    const float invn = 1.f / (CPG * L_DIM);
    float mu = S * invn;
    float var = SS * invn - mu * mu;
    meanp[bg] = mu;
    rstdp[bg] = rsqrtf(var + EPSV);
  }
}

// ------------- GN apply + transpose: x[b,c,l] -> hT[b,l,c] bf16 -------------
__global__ __launch_bounds__(256) void gn_apply_k(
    const float* __restrict__ x, const float* __restrict__ meanp,
    const float* __restrict__ rstdp, const float* __restrict__ gamma,
    const float* __restrict__ beta, u16* __restrict__ hT) {
  __shared__ float sm[64][65];
  const int b = blockIdx.z, c0 = blockIdx.y * 64, l0 = blockIdx.x * 64;
  const int tid = threadIdx.x;
#pragma unroll
  for (int p = 0; p < 4; ++p) {
    int cc = p * 16 + (tid >> 4);
    int ll = (tid & 15) * 4;
    float4 v = *(const float4*)(x + ((size_t)b * C_DIM + c0 + cc) * L_DIM + l0 + ll);
    int grp = (c0 + cc) >> 4;  // CPG = 16
    float rs = rstdp[b * NGROUPS + grp];
    float ga = gamma[c0 + cc] * rs;
    float be = beta[c0 + cc] - meanp[b * NGROUPS + grp] * ga;
    sm[cc][ll + 0] = v.x * ga + be;
    sm[cc][ll + 1] = v.y * ga + be;
    sm[cc][ll + 2] = v.z * ga + be;
    sm[cc][ll + 3] = v.w * ga + be;
  }
  __syncthreads();
#pragma unroll
  for (int i = 0; i < 8; ++i) {
    int w = tid + 256 * i;          // 2048 u32 words
    int ll = w >> 5;                // 32 words (64 channels) per l-row
    int cw = (w & 31) * 2;
    u32 pk = (u32)f2bf(sm[cw][ll]) | ((u32)f2bf(sm[cw + 1][ll]) << 16);
    *(u32*)(hT + ((size_t)b * L_DIM + l0 + ll) * C_DIM + c0 + cw) = pk;
  }
}

// ------- row softmax, wave-per-row (shuffle-only), 4 rows/block, in place ----
__global__ __launch_bounds__(256) void softmax_k(u16* __restrict__ S) {
  const int lane = threadIdx.x & 63;
  const size_t row = (size_t)blockIdx.x * 4 + (threadIdx.x >> 6);
  u16* r = S + row * L_DIM;
  float f[32];
  union { int4 v; u16 u[8]; } cv;
#pragma unroll
  for (int q = 0; q < 4; ++q) {
    cv.v = ((const int4*)r)[q * 64 + lane];
#pragma unroll
    for (int j = 0; j < 8; ++j) f[q * 8 + j] = bf2f(cv.u[j]);
  }
  float mx = f[0];
#pragma unroll
  for (int j = 1; j < 32; ++j) mx = fmaxf(mx, f[j]);
#pragma unroll
  for (int o = 1; o < 64; o <<= 1) mx = fmaxf(mx, __shfl_xor(mx, o));
  float s = 0.f;
#pragma unroll
  for (int j = 0; j < 32; ++j) { f[j] = __expf(f[j] - mx); s += f[j]; }
#pragma unroll
  for (int o = 1; o < 64; o <<= 1) s += __shfl_xor(s, o);
  float inv = 1.f / s;
#pragma unroll
  for (int q = 0; q < 4; ++q) {
#pragma unroll
    for (int j = 0; j < 8; ++j) cv.u[j] = f2bf(f[q * 8 + j] * inv);
    ((int4*)r)[q * 64 + lane] = cv.v;
  }
}

// ---------------- TN GEMM: C[m,n] = sum_k A[m,k]*B[n,k], K-contiguous -------
// T3-minimum pipeline: double-buffered LDS, stage(next) issued at TOP of each
// iteration (flies under compute), ONE barrier per K-step. global_load_lds
// width-16 with pre-swizzled source (rule 21), XOR-swizzled ds_read_b128,
// LDS-staged coalesced bf16 epilogue.
// MODE 0: bf16 out, + bias[n]       (fused q|k)
// MODE 1: bf16 out, + bias[m]       (v)
// MODE 2: bf16 out, * scale         (S)
// MODE 3: bf16 out                  (h2T)
// MODE 4: f32 out, + bias[m] + Xres (final, residual; direct 64B stores)
template <int MODE>
__global__ __launch_bounds__(256, 4) void gemm_tn(
    const u16* __restrict__ A, long sA, long lda,
    const u16* __restrict__ Bp, long sB, long ldb,
    void* __restrict__ Cv, long sC, int M, int N, int K,
    const float* __restrict__ bias, const float* __restrict__ Xres, long sX,
    float scale) {
  constexpr int BM = 128, BN = 128, BK = 64;
  __shared__ u16 smem[2][2 * BM * BK];  // 2 x 32KB double buffer
  const int bz = blockIdx.z;
  A += (long)bz * sA;
  Bp += (long)bz * sB;
  const int m0 = blockIdx.x * BM;
  const int n0 = blockIdx.y * BN;
  const int tid = threadIdx.x;
  const int lane = tid & 63;
  const int wid = tid >> 6;
  const int wr = wid >> 1, wc = wid & 1;  // 2x2 waves, 64x64 each

  f32x4 acc[4][4] = {};

  // stage one BK tile into buf: 16 segments of 1KB each for A and B.
  // LDS dest linear (wave-uniform base + lane*16); global source carries the
  // inverse XOR swizzle so swizzled ds_reads see correct data.
  const int srow = wid * 32 + (lane >> 3);
  const int scolb = ((lane & 7) << 4) ^ (((lane >> 3) & 7) << 4);
  auto stage = [&](int k0, int buf) {
    u16* As = smem[buf];
    u16* Bs = smem[buf] + BM * BK;
#pragma unroll
    for (int q = 0; q < 4; ++q) {
      int seg = wid * 4 + q;
      int row = srow + q * 8;
      const char* ga = (const char*)A + ((long)(m0 + row) * lda + k0) * 2 + scolb;
      __builtin_amdgcn_global_load_lds((gchar*)ga,
                                       (lchar*)((char*)As + seg * 1024), 16, 0, 0);
      const char* gb = (const char*)Bp + ((long)(n0 + row) * ldb + k0) * 2 + scolb;
      __builtin_amdgcn_global_load_lds((gchar*)gb,
                                       (lchar*)((char*)Bs + seg * 1024), 16, 0, 0);
    }
  };

  const int nkt = K / BK;
  stage(0, 0);
  int cur = 0;
  for (int kt = 0; kt < nkt; ++kt) {
    // barrier: drains vmcnt(0) -> buf[cur] tile landed (issued one full
    // compute phase ago); lgkm drain -> all waves done reading buf[cur^1].
    __syncthreads();
    if (kt + 1 < nkt) stage((kt + 1) * BK, cur ^ 1);  // flies under MFMA below
    const u16* As = smem[cur];
    const u16* Bs = smem[cur] + BM * BK;
#pragma unroll
    for (int ks = 0; ks < 2; ++ks) {
      bf16x8 af[4], bfv[4];
#pragma unroll
      for (int f = 0; f < 4; ++f) {
        int ra = wr * 64 + f * 16 + (lane & 15);
        int oa = (ra * 128 + ks * 64 + ((lane >> 4) * 16)) ^ ((ra & 7) << 4);
        af[f] = *(const bf16x8*)((const char*)As + oa);
        int rb = wc * 64 + f * 16 + (lane & 15);
        int ob = (rb * 128 + ks * 64 + ((lane >> 4) * 16)) ^ ((rb & 7) << 4);
        bfv[f] = *(const bf16x8*)((const char*)Bs + ob);
      }
#pragma unroll
      for (int i = 0; i < 4; ++i)
#pragma unroll
        for (int j = 0; j < 4; ++j)
          acc[i][j] = __builtin_amdgcn_mfma_f32_16x16x32_bf16(af[i], bfv[j],
                                                              acc[i][j], 0, 0, 0);
    }
    cur ^= 1;
  }

  const int mb = wr * 64 + ((lane >> 4) << 2);
  const int nb = wc * 64 + (lane & 15);
  if (MODE == 4) {
    // f32 out: 16 lanes x 4B = 64B full segments, direct store
#pragma unroll
    for (int i = 0; i < 4; ++i)
#pragma unroll
      for (int j = 0; j < 4; ++j)
#pragma unroll
        for (int r = 0; r < 4; ++r) {
          int m = m0 + mb + i * 16 + r;
          int n = n0 + nb + j * 16;
          long off = (long)m * N + n;
          ((float*)Cv)[(long)bz * sC + off] =
              acc[i][j][r] + bias[m] + Xres[(long)bz * sX + off];
        }
  } else {
    __syncthreads();       // all reads of smem done; reuse as C staging
    u16* Cs = smem[0];     // [128][128] bf16, XOR-swizzled rows
#pragma unroll
    for (int i = 0; i < 4; ++i)
#pragma unroll
      for (int j = 0; j < 4; ++j)
#pragma unroll
        for (int r = 0; r < 4; ++r) {
          float val = acc[i][j][r];
          int ml = mb + i * 16 + r;
          int nl = nb + j * 16;
          if (MODE == 0) val += bias[n0 + nl];
          if (MODE == 1) val += bias[m0 + ml];
          if (MODE == 2) val *= scale;
          int byt = (ml * 256 + nl * 2) ^ ((ml & 7) << 4);
          *(u16*)((char*)Cs + byt) = f2bf(val);
        }
    __syncthreads();
    // coalesced dwordx4 stores: 2048 int4 chunks, contiguous per 16 lanes
#pragma unroll
    for (int u = 0; u < 8; ++u) {
      int c = u * 256 + tid;
      int row = c >> 4, c4 = c & 15;
      int lb = (row * 256 + c4 * 16) ^ ((row & 7) << 4);
      int4 vv = *(const int4*)((const char*)Cs + lb);
      *(int4*)((u16*)Cv + (long)bz * sC + (long)(m0 + row) * N + n0 + c4 * 8) = vv;
    }
  }
}

extern "C" void kernel_launch(void* const* d_in, const int* in_sizes, int n_in,
                              void* d_out, int out_size, void* d_ws,
                              size_t ws_size, hipStream_t stream) {
  const float* x = (const float*)d_in[0];
  const float* Wq = (const float*)d_in[1];
  const float* bq = (const float*)d_in[2];
  const float* Wk = (const float*)d_in[3];
  const float* bk = (const float*)d_in[4];
  const float* Wv = (const float*)d_in[5];
  const float* bv = (const float*)d_in[6];
  const float* Wp = (const float*)d_in[7];
  const float* bp = (const float*)d_in[8];
  const float* gamma = (const float*)d_in[9];
  const float* beta = (const float*)d_in[10];
  float* out = (float*)d_out;

  const size_t BLC = (size_t)B_DIM * L_DIM * C_DIM;  // 8.39M elements
  const size_t BLL = (size_t)B_DIM * L_DIM * L_DIM;  // 33.6M elements
  const int CC = C_DIM * C_DIM;
  // ws layout (d_out written ONLY by the final GEMM):
  //   vbuf [0,16M) | qkT [16M,48M) | Sbuf [48M,112M) | weights+misc [112M..)
  //   hT  aliases Sbuf[0:16M)  (dead before S-GEMM writes Sbuf)
  //   h2T aliases qkT[0:16M)   (dead after S-GEMM reads qkT)
  u16* vbuf = (u16*)d_ws;            // [B][C][L]
  u16* qkT = vbuf + BLC;             // [B][L][1024] q|k fused
  u16* Sbuf = qkT + 2 * BLC;         // [B][L][L] scores->probs
  u16* hT = Sbuf;                    // alias: [B][L][C] normalized x
  u16* h2T = qkT;                    // alias: [B][L][C] attention out
  u16* wqkb = Sbuf + BLL;            // [1024][512] q rows then k rows
  u16* wvb = wqkb + 2 * CC;
  u16* wpb = wvb + CC;
  float* meanp = (float*)(wpb + CC);
  float* rstdp = meanp + B_DIM * NGROUPS;
  float* bqk = rstdp + B_DIM * NGROUPS;  // [1024] concat biases

  const long LC = (long)L_DIM * C_DIM;
  const long CL = (long)C_DIM * L_DIM;
  const long LL = (long)L_DIM * L_DIM;
  const long LQK = (long)L_DIM * 2 * C_DIM;
  const float scale = 1.0f / sqrtf((float)C_DIM);

  // weights -> bf16 + bias concat (single dispatch)
  prep_k<<<1025, 256, 0, stream>>>(Wq, Wk, Wv, Wp, bq, bk, wqkb, wvb, wpb, bqk);
  // GroupNorm
  gn_stats_k<<<B_DIM * NGROUPS, 256, 0, stream>>>(x, meanp, rstdp);
  gn_apply_k<<<dim3(L_DIM / 64, C_DIM / 64, B_DIM), 256, 0, stream>>>(
      x, meanp, rstdp, gamma, beta, hT);
  // qkT[l, 0:1024] = hT . [Wq;Wk]^T (+bqk[n])
  gemm_tn<0><<<dim3(L_DIM / 128, 2 * C_DIM / 128, B_DIM), 256, 0, stream>>>(
      hT, LC, C_DIM, wqkb, 0L, C_DIM, qkT, LQK, L_DIM, 2 * C_DIM, C_DIM,
      bqk, nullptr, 0L, 0.f);
  // v[o,l] = Wv . hT (+bv[m])
  gemm_tn<1><<<dim3(C_DIM / 128, L_DIM / 128, B_DIM), 256, 0, stream>>>(
      wvb, 0L, C_DIM, hT, LC, C_DIM, vbuf, CL, C_DIM, L_DIM, C_DIM,
      bv, nullptr, 0L, 0.f);
  // S[l,m] = (q . k^T) * scale   (hT dead from here; Sbuf overwrites it)
  gemm_tn<2><<<dim3(L_DIM / 128, L_DIM / 128, B_DIM), 256, 0, stream>>>(
      qkT, LQK, 2 * C_DIM, qkT + C_DIM, LQK, 2 * C_DIM, Sbuf, LL,
      L_DIM, L_DIM, C_DIM, nullptr, nullptr, 0L, scale);
  // softmax rows (wave-per-row, 4 rows/block)
  softmax_k<<<B_DIM * L_DIM / 4, 256, 0, stream>>>(Sbuf);
  // h2T[l,c] = P . v^T   (qkT dead from here; h2T overwrites its first 16MB)
  gemm_tn<3><<<dim3(L_DIM / 128, C_DIM / 128, B_DIM), 256, 0, stream>>>(
      Sbuf, LL, L_DIM, vbuf, CL, L_DIM, h2T, LC, L_DIM, C_DIM, L_DIM,
      nullptr, nullptr, 0L, 0.f);
  // out[o,l] = Wp . h2T + bp[m] + x   (sole write to d_out)
  gemm_tn<4><<<dim3(C_DIM / 128, L_DIM / 128, B_DIM), 256, 0, stream>>>(
      wpb, 0L, C_DIM, h2T, LC, C_DIM, out, CL, C_DIM, L_DIM, C_DIM,
      bp, x, CL, 0.f);
}

// Round 7
// 281.243 us; speedup vs baseline: 1.0794x; 1.0794x over previous
//
#include <hip/hip_runtime.h>
#include <cstdint>

#define B_DIM 8
#define C_DIM 512
#define L_DIM 2048
#define NGROUPS 32
#define CPG 16
#define EPSV 1e-6f

typedef unsigned short u16;
typedef unsigned int u32;
typedef __attribute__((ext_vector_type(4))) float f32x4;
typedef __attribute__((ext_vector_type(8))) short bf16x8;
typedef const __attribute__((address_space(1))) char gchar;
typedef __attribute__((address_space(3))) char lchar;

__device__ __forceinline__ u16 f2bf(float f) {
  u32 u = __float_as_uint(f);
  u = (u + 0x7fffu + ((u >> 16) & 1u)) >> 16;
  return (u16)u;
}
__device__ __forceinline__ float bf2f(u16 h) {
  return __uint_as_float(((u32)h) << 16);
}

// -------- fused prep: 4x weight fp32->bf16 + bias concat (1 dispatch) --------
__global__ __launch_bounds__(256) void prep_k(
    const float* __restrict__ Wq, const float* __restrict__ Wk,
    const float* __restrict__ Wv, const float* __restrict__ Wp,
    const float* __restrict__ bq, const float* __restrict__ bk,
    u16* __restrict__ wqkb, u16* __restrict__ wvb, u16* __restrict__ wpb,
    float* __restrict__ bqk) {
  const int g = blockIdx.x;
  if (g < 1024) {
    const int w = g >> 8;
    const float* src = w == 0 ? Wq : w == 1 ? Wk : w == 2 ? Wv : Wp;
    u16* dst = w == 0 ? wqkb : w == 1 ? wqkb + C_DIM * C_DIM : w == 2 ? wvb : wpb;
    int i = (g & 255) * 256 + threadIdx.x;  // over CC/4 float4 chunks
    float4 v = ((const float4*)src)[i];
    int2 o;
    o.x = (int)((u32)f2bf(v.x) | ((u32)f2bf(v.y) << 16));
    o.y = (int)((u32)f2bf(v.z) | ((u32)f2bf(v.w) << 16));
    ((int2*)dst)[i] = o;
  } else {
#pragma unroll
    for (int q = 0; q < 4; ++q) {
      int idx = q * 256 + threadIdx.x;
      bqk[idx] = idx < C_DIM ? bq[idx] : bk[idx - C_DIM];
    }
  }
}

// ---------------- GroupNorm stats: one block per (b,g) ----------------
__global__ __launch_bounds__(256) void gn_stats_k(const float* __restrict__ x,
                                                  float* __restrict__ meanp,
                                                  float* __restrict__ rstdp) {
  const int bg = blockIdx.x;
  const float4* xv = (const float4*)(x + (size_t)bg * CPG * L_DIM);
  const int tid = threadIdx.x;
  float s = 0.f, ss = 0.f;
  for (int i = tid; i < CPG * L_DIM / 4; i += 256) {
    float4 v = xv[i];
    s += v.x + v.y + v.z + v.w;
    ss += v.x * v.x + v.y * v.y + v.z * v.z + v.w * v.w;
  }
#pragma unroll
  for (int o = 32; o > 0; o >>= 1) {
    s += __shfl_down(s, o);
    ss += __shfl_down(ss, o);
  }
  __shared__ float r1[4], r2[4];
  if ((tid & 63) == 0) { r1[tid >> 6] = s; r2[tid >> 6] = ss; }
  __syncthreads();
  if (tid == 0) {
    float S = r1[0] + r1[1] + r1[2] + r1[3];
    float SS = r2[0] + r2[1] + r2[2] + r2[3];
    const float invn = 1.f / (CPG * L_DIM);
    float mu = S * invn;
    float var = SS * invn - mu * mu;
    meanp[bg] = mu;
    rstdp[bg] = rsqrtf(var + EPSV);
  }
}

// ------------- GN apply + transpose: x[b,c,l] -> hT[b,l,c] bf16 -------------
__global__ __launch_bounds__(256) void gn_apply_k(
    const float* __restrict__ x, const float* __restrict__ meanp,
    const float* __restrict__ rstdp, const float* __restrict__ gamma,
    const float* __restrict__ beta, u16* __restrict__ hT) {
  __shared__ float sm[64][65];
  const int b = blockIdx.z, c0 = blockIdx.y * 64, l0 = blockIdx.x * 64;
  const int tid = threadIdx.x;
#pragma unroll
  for (int p = 0; p < 4; ++p) {
    int cc = p * 16 + (tid >> 4);
    int ll = (tid & 15) * 4;
    float4 v = *(const float4*)(x + ((size_t)b * C_DIM + c0 + cc) * L_DIM + l0 + ll);
    int grp = (c0 + cc) >> 4;  // CPG = 16
    float rs = rstdp[b * NGROUPS + grp];
    float ga = gamma[c0 + cc] * rs;
    float be = beta[c0 + cc] - meanp[b * NGROUPS + grp] * ga;
    sm[cc][ll + 0] = v.x * ga + be;
    sm[cc][ll + 1] = v.y * ga + be;
    sm[cc][ll + 2] = v.z * ga + be;
    sm[cc][ll + 3] = v.w * ga + be;
  }
  __syncthreads();
#pragma unroll
  for (int i = 0; i < 8; ++i) {
    int w = tid + 256 * i;          // 2048 u32 words
    int ll = w >> 5;                // 32 words (64 channels) per l-row
    int cw = (w & 31) * 2;
    u32 pk = (u32)f2bf(sm[cw][ll]) | ((u32)f2bf(sm[cw + 1][ll]) << 16);
    *(u32*)(hT + ((size_t)b * L_DIM + l0 + ll) * C_DIM + c0 + cw) = pk;
  }
}

// ------- row softmax, wave-per-row (shuffle-only), 4 rows/block, in place ----
__global__ __launch_bounds__(256) void softmax_k(u16* __restrict__ S) {
  const int lane = threadIdx.x & 63;
  const size_t row = (size_t)blockIdx.x * 4 + (threadIdx.x >> 6);
  u16* r = S + row * L_DIM;
  float f[32];
  union { int4 v; u16 u[8]; } cv;
#pragma unroll
  for (int q = 0; q < 4; ++q) {
    cv.v = ((const int4*)r)[q * 64 + lane];
#pragma unroll
    for (int j = 0; j < 8; ++j) f[q * 8 + j] = bf2f(cv.u[j]);
  }
  float mx = f[0];
#pragma unroll
  for (int j = 1; j < 32; ++j) mx = fmaxf(mx, f[j]);
#pragma unroll
  for (int o = 1; o < 64; o <<= 1) mx = fmaxf(mx, __shfl_xor(mx, o));
  float s = 0.f;
#pragma unroll
  for (int j = 0; j < 32; ++j) { f[j] = __expf(f[j] - mx); s += f[j]; }
#pragma unroll
  for (int o = 1; o < 64; o <<= 1) s += __shfl_xor(s, o);
  float inv = 1.f / s;
#pragma unroll
  for (int q = 0; q < 4; ++q) {
#pragma unroll
    for (int j = 0; j < 8; ++j) cv.u[j] = f2bf(f[q * 8 + j] * inv);
    ((int4*)r)[q * 64 + lane] = cv.v;
  }
}

// ---------------- TN GEMM: C[m,n] = sum_k A[m,k]*B[n,k], K-contiguous -------
// Double-buffered LDS with STATIC buffer indices (K-loop unrolled x2):
// stage(next) issued right after the barrier, flies under the MFMA phase;
// one barrier per K-step; all LDS addresses constant-folded.
// global_load_lds width-16, pre-swizzled source (rule 21), XOR-swizzled
// ds_read_b128, LDS-staged coalesced bf16 epilogue.
// MODE 0: bf16 out, + bias[n]       (fused q|k)
// MODE 1: bf16 out, + bias[m]       (v)
// MODE 2: bf16 out, * scale         (S)
// MODE 3: bf16 out                  (h2T)
// MODE 4: f32 out, + bias[m] + Xres (final, residual; direct 64B stores)
template <int MODE>
__global__ __launch_bounds__(256, 2) void gemm_tn(
    const u16* __restrict__ A, long sA, long lda,
    const u16* __restrict__ Bp, long sB, long ldb,
    void* __restrict__ Cv, long sC, int M, int N, int K,
    const float* __restrict__ bias, const float* __restrict__ Xres, long sX,
    float scale) {
  constexpr int BM = 128, BN = 128, BK = 64;
  __shared__ u16 smem0[2 * BM * BK];  // buf0: As|Bs
  __shared__ u16 smem1[2 * BM * BK];  // buf1: As|Bs
  const int bz = blockIdx.z;
  A += (long)bz * sA;
  Bp += (long)bz * sB;
  const int m0 = blockIdx.x * BM;
  const int n0 = blockIdx.y * BN;
  const int tid = threadIdx.x;
  const int lane = tid & 63;
  const int wid = tid >> 6;
  const int wr = wid >> 1, wc = wid & 1;  // 2x2 waves, 64x64 each

  f32x4 acc[4][4] = {};

  // stage one BK tile into a buffer (compile-time base): 16 x 1KB segments
  // each for A and B. LDS dest linear (wave-uniform base + lane*16); global
  // source carries the inverse XOR swizzle so swizzled ds_reads see correct
  // data (rule 21).
  const int srow = wid * 32 + (lane >> 3);
  const int scolb = ((lane & 7) << 4) ^ (((lane >> 3) & 7) << 4);
  auto stage = [&](int k0, u16* buf) {
    u16* As = buf;
    u16* Bs = buf + BM * BK;
#pragma unroll
    for (int q = 0; q < 4; ++q) {
      int seg = wid * 4 + q;
      int row = srow + q * 8;
      const char* ga = (const char*)A + ((long)(m0 + row) * lda + k0) * 2 + scolb;
      __builtin_amdgcn_global_load_lds((gchar*)ga,
                                       (lchar*)((char*)As + seg * 1024), 16, 0, 0);
      const char* gb = (const char*)Bp + ((long)(n0 + row) * ldb + k0) * 2 + scolb;
      __builtin_amdgcn_global_load_lds((gchar*)gb,
                                       (lchar*)((char*)Bs + seg * 1024), 16, 0, 0);
    }
  };
  auto compute = [&](const u16* buf) {
    const u16* As = buf;
    const u16* Bs = buf + BM * BK;
#pragma unroll
    for (int ks = 0; ks < 2; ++ks) {
      bf16x8 af[4], bfv[4];
#pragma unroll
      for (int f = 0; f < 4; ++f) {
        int ra = wr * 64 + f * 16 + (lane & 15);
        int oa = (ra * 128 + ks * 64 + ((lane >> 4) * 16)) ^ ((ra & 7) << 4);
        af[f] = *(const bf16x8*)((const char*)As + oa);
        int rb = wc * 64 + f * 16 + (lane & 15);
        int ob = (rb * 128 + ks * 64 + ((lane >> 4) * 16)) ^ ((rb & 7) << 4);
        bfv[f] = *(const bf16x8*)((const char*)Bs + ob);
      }
#pragma unroll
      for (int i = 0; i < 4; ++i)
#pragma unroll
        for (int j = 0; j < 4; ++j)
          acc[i][j] = __builtin_amdgcn_mfma_f32_16x16x32_bf16(af[i], bfv[j],
                                                              acc[i][j], 0, 0, 0);
    }
  };

  const int nkt = K / BK;  // always even here (K = 512 or 2048)
  stage(0, smem0);
  for (int kt = 0; kt < nkt; kt += 2) {
    // barrier: vmcnt(0) drained -> current tile landed (issued one full
    // compute phase ago); lgkm drained -> prior-phase reads of the buffer
    // we're about to overwrite are complete.
    __syncthreads();
    if (kt + 1 < nkt) stage((kt + 1) * BK, smem1);  // flies under compute
    compute(smem0);
    __syncthreads();
    if (kt + 2 < nkt) stage((kt + 2) * BK, smem0);
    compute(smem1);
  }

  const int mb = wr * 64 + ((lane >> 4) << 2);
  const int nb = wc * 64 + (lane & 15);
  if (MODE == 4) {
    // f32 out: 16 lanes x 4B = 64B full segments, direct store
#pragma unroll
    for (int i = 0; i < 4; ++i)
#pragma unroll
      for (int j = 0; j < 4; ++j)
#pragma unroll
        for (int r = 0; r < 4; ++r) {
          int m = m0 + mb + i * 16 + r;
          int n = n0 + nb + j * 16;
          long off = (long)m * N + n;
          ((float*)Cv)[(long)bz * sC + off] =
              acc[i][j][r] + bias[m] + Xres[(long)bz * sX + off];
        }
  } else {
    __syncthreads();       // all reads of smem done; reuse as C staging
    u16* Cs = smem0;       // [128][128] bf16, XOR-swizzled rows
#pragma unroll
    for (int i = 0; i < 4; ++i)
#pragma unroll
      for (int j = 0; j < 4; ++j)
#pragma unroll
        for (int r = 0; r < 4; ++r) {
          float val = acc[i][j][r];
          int ml = mb + i * 16 + r;
          int nl = nb + j * 16;
          if (MODE == 0) val += bias[n0 + nl];
          if (MODE == 1) val += bias[m0 + ml];
          if (MODE == 2) val *= scale;
          int byt = (ml * 256 + nl * 2) ^ ((ml & 7) << 4);
          *(u16*)((char*)Cs + byt) = f2bf(val);
        }
    __syncthreads();
    // coalesced dwordx4 stores: 2048 int4 chunks, contiguous per 16 lanes
#pragma unroll
    for (int u = 0; u < 8; ++u) {
      int c = u * 256 + tid;
      int row = c >> 4, c4 = c & 15;
      int lb = (row * 256 + c4 * 16) ^ ((row & 7) << 4);
      int4 vv = *(const int4*)((const char*)Cs + lb);
      *(int4*)((u16*)Cv + (long)bz * sC + (long)(m0 + row) * N + n0 + c4 * 8) = vv;
    }
  }
}

extern "C" void kernel_launch(void* const* d_in, const int* in_sizes, int n_in,
                              void* d_out, int out_size, void* d_ws,
                              size_t ws_size, hipStream_t stream) {
  const float* x = (const float*)d_in[0];
  const float* Wq = (const float*)d_in[1];
  const float* bq = (const float*)d_in[2];
  const float* Wk = (const float*)d_in[3];
  const float* bk = (const float*)d_in[4];
  const float* Wv = (const float*)d_in[5];
  const float* bv = (const float*)d_in[6];
  const float* Wp = (const float*)d_in[7];
  const float* bp = (const float*)d_in[8];
  const float* gamma = (const float*)d_in[9];
  const float* beta = (const float*)d_in[10];
  float* out = (float*)d_out;

  const size_t BLC = (size_t)B_DIM * L_DIM * C_DIM;  // 8.39M elements
  const size_t BLL = (size_t)B_DIM * L_DIM * L_DIM;  // 33.6M elements
  const int CC = C_DIM * C_DIM;
  // ws layout (d_out written ONLY by the final GEMM):
  //   vbuf [0,16M) | qkT [16M,48M) | Sbuf [48M,112M) | weights+misc [112M..)
  //   hT  aliases Sbuf[0:16M)  (dead before S-GEMM writes Sbuf)
  //   h2T aliases qkT[0:16M)   (dead after S-GEMM reads qkT)
  u16* vbuf = (u16*)d_ws;            // [B][C][L]
  u16* qkT = vbuf + BLC;             // [B][L][1024] q|k fused
  u16* Sbuf = qkT + 2 * BLC;         // [B][L][L] scores->probs
  u16* hT = Sbuf;                    // alias: [B][L][C] normalized x
  u16* h2T = qkT;                    // alias: [B][L][C] attention out
  u16* wqkb = Sbuf + BLL;            // [1024][512] q rows then k rows
  u16* wvb = wqkb + 2 * CC;
  u16* wpb = wvb + CC;
  float* meanp = (float*)(wpb + CC);
  float* rstdp = meanp + B_DIM * NGROUPS;
  float* bqk = rstdp + B_DIM * NGROUPS;  // [1024] concat biases

  const long LC = (long)L_DIM * C_DIM;
  const long CL = (long)C_DIM * L_DIM;
  const long LL = (long)L_DIM * L_DIM;
  const long LQK = (long)L_DIM * 2 * C_DIM;
  const float scale = 1.0f / sqrtf((float)C_DIM);

  // weights -> bf16 + bias concat (single dispatch)
  prep_k<<<1025, 256, 0, stream>>>(Wq, Wk, Wv, Wp, bq, bk, wqkb, wvb, wpb, bqk);
  // GroupNorm
  gn_stats_k<<<B_DIM * NGROUPS, 256, 0, stream>>>(x, meanp, rstdp);
  gn_apply_k<<<dim3(L_DIM / 64, C_DIM / 64, B_DIM), 256, 0, stream>>>(
      x, meanp, rstdp, gamma, beta, hT);
  // qkT[l, 0:1024] = hT . [Wq;Wk]^T (+bqk[n])
  gemm_tn<0><<<dim3(L_DIM / 128, 2 * C_DIM / 128, B_DIM), 256, 0, stream>>>(
      hT, LC, C_DIM, wqkb, 0L, C_DIM, qkT, LQK, L_DIM, 2 * C_DIM, C_DIM,
      bqk, nullptr, 0L, 0.f);
  // v[o,l] = Wv . hT (+bv[m])
  gemm_tn<1><<<dim3(C_DIM / 128, L_DIM / 128, B_DIM), 256, 0, stream>>>(
      wvb, 0L, C_DIM, hT, LC, C_DIM, vbuf, CL, C_DIM, L_DIM, C_DIM,
      bv, nullptr, 0L, 0.f);
  // S[l,m] = (q . k^T) * scale   (hT dead from here; Sbuf overwrites it)
  gemm_tn<2><<<dim3(L_DIM / 128, L_DIM / 128, B_DIM), 256, 0, stream>>>(
      qkT, LQK, 2 * C_DIM, qkT + C_DIM, LQK, 2 * C_DIM, Sbuf, LL,
      L_DIM, L_DIM, C_DIM, nullptr, nullptr, 0L, scale);
  // softmax rows (wave-per-row, 4 rows/block)
  softmax_k<<<B_DIM * L_DIM / 4, 256, 0, stream>>>(Sbuf);
  // h2T[l,c] = P . v^T   (qkT dead from here; h2T overwrites its first 16MB)
  gemm_tn<3><<<dim3(L_DIM / 128, C_DIM / 128, B_DIM), 256, 0, stream>>>(
      Sbuf, LL, L_DIM, vbuf, CL, L_DIM, h2T, LC, L_DIM, C_DIM, L_DIM,
      nullptr, nullptr, 0L, 0.f);
  // out[o,l] = Wp . h2T + bp[m] + x   (sole write to d_out)
  gemm_tn<4><<<dim3(C_DIM / 128, L_DIM / 128, B_DIM), 256, 0, stream>>>(
      wpb, 0L, C_DIM, h2T, LC, C_DIM, out, CL, C_DIM, L_DIM, C_DIM,
      bp, x, CL, 0.f);
}